// Round 1
// baseline (537.469 us; speedup 1.0000x reference)
//
#include <hip/hip_runtime.h>

#define N_NODES 50000
#define N_EDGES 800000
#define D 128

typedef unsigned short ushort_t;
typedef __bf16 bf16x8 __attribute__((ext_vector_type(8)));
typedef float f32x4 __attribute__((ext_vector_type(4)));

__device__ __forceinline__ ushort_t f2bf(float f) {
    unsigned u = __builtin_bit_cast(unsigned, f);
    u += 0x7FFFu + ((u >> 16) & 1u);   // round-to-nearest-even
    return (ushort_t)(u >> 16);
}

// ---------- graph setup ----------
__global__ __launch_bounds__(256) void k_deg(const int* __restrict__ col, int* __restrict__ deg) {
    int e = blockIdx.x * 256 + threadIdx.x;
    if (e < N_EDGES) atomicAdd(&deg[col[e]], 1);
}

__global__ __launch_bounds__(256) void k_invdeg(const int* __restrict__ deg, float* __restrict__ inv_deg) {
    int i = blockIdx.x * 256 + threadIdx.x;
    if (i < N_NODES) inv_deg[i] = 1.0f / (float)deg[i];
}

__global__ __launch_bounds__(256) void k_s(const int* __restrict__ row, const int* __restrict__ col,
                                           const float* __restrict__ inv_deg, float* __restrict__ s) {
    int e = blockIdx.x * 256 + threadIdx.x;
    if (e < N_EDGES) atomicAdd(&s[col[e]], inv_deg[row[e]]);
}

// exclusive scan of deg[50000] -> off, single block of 1024
__global__ __launch_bounds__(1024) void k_scan(const int* __restrict__ deg, int* __restrict__ off) {
    __shared__ int sums[1024];
    int t = threadIdx.x;
    const int CH = 49;                       // 49*1024 = 50176 >= 50000
    int start = t * CH;
    int end = min(start + CH, N_NODES);
    int sum = 0;
    for (int i = start; i < end; ++i) sum += deg[i];
    sums[t] = sum;
    __syncthreads();
    for (int o = 1; o < 1024; o <<= 1) {
        int add = (t >= o) ? sums[t - o] : 0;
        __syncthreads();
        sums[t] += add;
        __syncthreads();
    }
    int run = sums[t] - sum;                 // exclusive base for this thread
    for (int i = start; i < end; ++i) { off[i] = run; run += deg[i]; }
}

__global__ __launch_bounds__(256) void k_fill(const int* __restrict__ row, const int* __restrict__ col,
                                              const int* __restrict__ off, int* __restrict__ cursor,
                                              int* __restrict__ csr) {
    int e = blockIdx.x * 256 + threadIdx.x;
    if (e < N_EDGES) {
        int c = col[e];
        int p = atomicAdd(&cursor[c], 1);
        csr[off[c] + p] = row[e];
    }
}

__global__ __launch_bounds__(256) void k_cast(const float* __restrict__ x, ushort_t* __restrict__ xb) {
    int i = blockIdx.x * 256 + threadIdx.x;    // one float4 per thread
    int base = i * 4;
    if (base < N_NODES * D) {
        float4 v = *(const float4*)(x + base);
        ushort_t o0 = f2bf(v.x), o1 = f2bf(v.y), o2 = f2bf(v.z), o3 = f2bf(v.w);
        ushort_t* p = xb + base;
        p[0] = o0; p[1] = o1; p[2] = o2; p[3] = o3;
    }
}

// ---------- fused GEMM: P[m, 0:128]=x@W1.T, P[m,128:256]=x@W2[:, :d].T,
// P[m,256:384]=inv_deg[m] * (x@W2[:, d:].T).  blockIdx.y selects chunk. ----------
__global__ __launch_bounds__(256) void k_gemm(const ushort_t* __restrict__ xb,
                                              const float* __restrict__ W1,
                                              const float* __restrict__ W2,
                                              const float* __restrict__ inv_deg,
                                              float* __restrict__ P) {
    __shared__ __align__(16) ushort_t As[64][136];   // +8 pad -> 272B row, 2-way banks
    __shared__ __align__(16) ushort_t Bs[128][136];
    const int m0 = blockIdx.x * 64;
    const int y  = blockIdx.y;                        // 0: W1, 1: W2 left, 2: W2 right
    const float* Bp = (y == 0) ? W1 : (y == 1 ? W2 : W2 + 128);
    const int strideW = (y == 0) ? 128 : 256;
    const int tid = threadIdx.x;

    // stage A: 64 rows x 128 bf16 (16B per thread x 4)
    #pragma unroll
    for (int it = 0; it < 4; ++it) {
        int chunk = tid + it * 256;           // 0..1023
        int r = chunk >> 4, kc = chunk & 15;
        uint4 v = make_uint4(0, 0, 0, 0);
        int gm = m0 + r;
        if (gm < N_NODES) v = *(const uint4*)(xb + gm * D + kc * 8);
        *(uint4*)&As[r][kc * 8] = v;
    }
    // stage B: 128 rows x 128 fp32 -> bf16
    #pragma unroll
    for (int it = 0; it < 16; ++it) {
        int c = tid + it * 256;               // float4 chunks, 0..4095
        int r = c >> 5, kc = c & 31;
        float4 v = *(const float4*)(Bp + r * strideW + kc * 4);
        ushort_t tmp[4] = { f2bf(v.x), f2bf(v.y), f2bf(v.z), f2bf(v.w) };
        *(uint2*)&Bs[r][kc * 4] = *(const uint2*)tmp;
    }
    __syncthreads();

    const int w = tid >> 6, lane = tid & 63, quad = lane >> 4, r16 = lane & 15;
    f32x4 acc[8];
    #pragma unroll
    for (int nt = 0; nt < 8; ++nt) acc[nt] = (f32x4){0.f, 0.f, 0.f, 0.f};
    const int arow = w * 16 + r16;
    #pragma unroll
    for (int k0 = 0; k0 < 128; k0 += 32) {
        bf16x8 a = __builtin_bit_cast(bf16x8, *(const uint4*)&As[arow][k0 + quad * 8]);
        #pragma unroll
        for (int nt = 0; nt < 8; ++nt) {
            bf16x8 b = __builtin_bit_cast(bf16x8, *(const uint4*)&Bs[nt * 16 + r16][k0 + quad * 8]);
            acc[nt] = __builtin_amdgcn_mfma_f32_16x16x32_bf16(a, b, acc[nt], 0, 0, 0);
        }
    }
    // epilogue: C[m = quad*4+reg][n = nt*16 + r16]
    float sc[4];
    #pragma unroll
    for (int r = 0; r < 4; ++r) {
        int gm = m0 + w * 16 + quad * 4 + r;
        sc[r] = (y == 2 && gm < N_NODES) ? inv_deg[gm] : 1.0f;
    }
    #pragma unroll
    for (int nt = 0; nt < 8; ++nt) {
        #pragma unroll
        for (int r = 0; r < 4; ++r) {
            int gm = m0 + w * 16 + quad * 4 + r;
            if (gm < N_NODES) {
                int colg = y * 128 + nt * 16 + r16;
                P[(size_t)gm * 384 + colg] = acc[nt][r] * sc[r];
            }
        }
    }
}

// ---------- per-node aggregation + GELU. One wave per node, 2 dims/lane ----------
__global__ __launch_bounds__(256) void k_agg(const float* __restrict__ P,
                                             const int* __restrict__ off,
                                             const int* __restrict__ deg,
                                             const int* __restrict__ csr,
                                             const float* __restrict__ s,
                                             const float* __restrict__ bias,
                                             float* __restrict__ out_f32,
                                             ushort_t* __restrict__ out_bf16,
                                             int write_bf16) {
    int node = blockIdx.x * 4 + (threadIdx.x >> 6);
    int lane = threadIdx.x & 63;
    if (node >= N_NODES) return;
    const float* Pr = P + (size_t)node * 384;
    float2 lin = *(const float2*)(Pr + 2 * lane);
    float2 pi  = *(const float2*)(Pr + 128 + 2 * lane);
    float  si  = s[node];
    float2 bv  = *(const float2*)(bias + 2 * lane);
    float a0 = lin.x + bv.x - si * pi.x;
    float a1 = lin.y + bv.y - si * pi.y;
    int e0 = off[node], ne = deg[node];
    int src = (ne > 0) ? csr[e0] : 0;
    for (int j = 0; j < ne; ++j) {
        int nsrc = (j + 1 < ne) ? csr[e0 + j + 1] : 0;
        float2 pj = *(const float2*)(P + (size_t)src * 384 + 256 + 2 * lane);  // pre-scaled by inv_deg
        a0 -= pj.x;
        a1 -= pj.y;
        src = nsrc;
    }
    // exact GELU: 0.5*x*(1+erf(x/sqrt(2)))
    float g0 = 0.5f * a0 * (1.0f + erff(a0 * 0.70710678118654752440f));
    float g1 = 0.5f * a1 * (1.0f + erff(a1 * 0.70710678118654752440f));
    if (write_bf16) {
        ushort_t tmp[2] = { f2bf(g0), f2bf(g1) };
        *(unsigned*)(out_bf16 + (size_t)node * D + 2 * lane) = *(const unsigned*)tmp;
    } else {
        *(float2*)(out_f32 + (size_t)node * D + 2 * lane) = make_float2(g0, g1);
    }
}

extern "C" void kernel_launch(void* const* d_in, const int* in_sizes, int n_in,
                              void* d_out, int out_size, void* d_ws, size_t ws_size,
                              hipStream_t stream) {
    const float* x      = (const float*)d_in[0];
    const int*   ei     = (const int*)d_in[1];
    const int*   rowp   = ei;
    const int*   colp   = ei + N_EDGES;
    const float* W1s    = (const float*)d_in[2];
    const float* W2s    = (const float*)d_in[3];
    const float* biases = (const float*)d_in[4];
    float* out = (float*)d_out;

    // workspace carve (256B aligned)
    char* ws = (char*)d_ws;
    size_t o = 0;
    auto carve = [&](size_t bytes) -> void* {
        void* p = ws + o;
        o = (o + bytes + 255) & ~(size_t)255;
        return p;
    };
    int*      deg     = (int*)carve(N_NODES * 4);
    int*      cursor  = (int*)carve(N_NODES * 4);
    float*    inv_deg = (float*)carve(N_NODES * 4);
    float*    s       = (float*)carve(N_NODES * 4);
    int*      off     = (int*)carve(N_NODES * 4);
    int*      csr     = (int*)carve(N_EDGES * 4);
    ushort_t* xb      = (ushort_t*)carve((size_t)N_NODES * D * 2);
    float*    P       = (float*)carve((size_t)N_NODES * 384 * 4);
    if (o > ws_size) return;  // ws too small -> output stays zero (diagnostic: absmax == 10.875)

    hipMemsetAsync(deg, 0, N_NODES * 4, stream);
    hipMemsetAsync(cursor, 0, N_NODES * 4, stream);
    hipMemsetAsync(s, 0, N_NODES * 4, stream);

    const int EB = (N_EDGES + 255) / 256;
    const int NB = (N_NODES + 255) / 256;
    k_deg<<<EB, 256, 0, stream>>>(colp, deg);
    k_invdeg<<<NB, 256, 0, stream>>>(deg, inv_deg);
    k_s<<<EB, 256, 0, stream>>>(rowp, colp, inv_deg, s);
    k_scan<<<1, 1024, 0, stream>>>(deg, off);
    k_fill<<<EB, 256, 0, stream>>>(rowp, colp, off, cursor, csr);
    k_cast<<<(N_NODES * D / 4 + 255) / 256, 256, 0, stream>>>(x, xb);

    dim3 ggrid((N_NODES + 63) / 64, 3);
    const int AB = (N_NODES + 3) / 4;
    for (int k = 0; k < 2; ++k) {
        k_gemm<<<ggrid, 256, 0, stream>>>(xb, W1s + k * 128 * 128, W2s + k * 128 * 256, inv_deg, P);
        k_agg<<<AB, 256, 0, stream>>>(P, off, deg, csr, s, biases + k * 128,
                                      (k == 1) ? out : nullptr, xb, (k == 0) ? 1 : 0);
    }
}

// Round 2
// 322.178 us; speedup vs baseline: 1.6682x; 1.6682x over previous
//
#include <hip/hip_runtime.h>

#define N_NODES 50000
#define N_EDGES 800000
#define D 128
#define NB2 196   // ceil(N_NODES/256)

typedef unsigned short ushort_t;
typedef __bf16 bf16x8 __attribute__((ext_vector_type(8)));
typedef float f32x4 __attribute__((ext_vector_type(4)));

__device__ __forceinline__ ushort_t f2bf(float f) {
    unsigned u = __builtin_bit_cast(unsigned, f);
    u += 0x7FFFu + ((u >> 16) & 1u);   // round-to-nearest-even
    return (ushort_t)(u >> 16);
}
__device__ __forceinline__ float bf2f(unsigned h16) {
    return __builtin_bit_cast(float, h16 << 16);
}

// ---------- graph setup ----------
__global__ __launch_bounds__(256) void k_deg(const int* __restrict__ col, int* __restrict__ deg) {
    int e = blockIdx.x * 256 + threadIdx.x;
    if (e < N_EDGES) atomicAdd(&deg[col[e]], 1);
}

__global__ __launch_bounds__(256) void k_cast(const float* __restrict__ x, ushort_t* __restrict__ xb) {
    int i = blockIdx.x * 256 + threadIdx.x;    // one float4 per thread
    int base = i * 4;
    if (base < N_NODES * D) {
        float4 v = *(const float4*)(x + base);
        ushort_t tmp[4] = { f2bf(v.x), f2bf(v.y), f2bf(v.z), f2bf(v.w) };
        *(uint2*)(xb + base) = *(const uint2*)tmp;
    }
}

// 3-phase coalesced exclusive scan of deg -> off; also seeds cursor and inv_deg
__global__ __launch_bounds__(256) void k_scan1(const int* __restrict__ deg, int* __restrict__ bsum) {
    int i = blockIdx.x * 256 + threadIdx.x;
    int v = (i < N_NODES) ? deg[i] : 0;
    #pragma unroll
    for (int o = 32; o > 0; o >>= 1) v += __shfl_down(v, o, 64);
    __shared__ int wsum[4];
    if ((threadIdx.x & 63) == 0) wsum[threadIdx.x >> 6] = v;
    __syncthreads();
    if (threadIdx.x == 0) bsum[blockIdx.x] = wsum[0] + wsum[1] + wsum[2] + wsum[3];
}

__global__ __launch_bounds__(256) void k_scan2(const int* __restrict__ bsum, int* __restrict__ boff) {
    __shared__ int sm[256];
    int t = threadIdx.x;
    int v = (t < NB2) ? bsum[t] : 0;
    sm[t] = v;
    __syncthreads();
    for (int o = 1; o < 256; o <<= 1) {
        int add = (t >= o) ? sm[t - o] : 0;
        __syncthreads();
        sm[t] += add;
        __syncthreads();
    }
    if (t < NB2) boff[t] = sm[t] - v;   // exclusive
}

__global__ __launch_bounds__(256) void k_scan3(const int* __restrict__ deg, const int* __restrict__ boff,
                                               int* __restrict__ off, int* __restrict__ cursor,
                                               float* __restrict__ inv_deg) {
    __shared__ int sm[256];
    int t = threadIdx.x;
    int i = blockIdx.x * 256 + t;
    int d = (i < N_NODES) ? deg[i] : 0;
    sm[t] = d;
    __syncthreads();
    for (int o = 1; o < 256; o <<= 1) {
        int add = (t >= o) ? sm[t - o] : 0;
        __syncthreads();
        sm[t] += add;
        __syncthreads();
    }
    if (i < N_NODES) {
        int excl = sm[t] - d + boff[blockIdx.x];
        off[i] = excl;
        cursor[i] = excl;
        inv_deg[i] = 1.0f / (float)d;   // deg >= 1 guaranteed by construction
    }
}

// fused: CSR fill (cursor pre-seeded with off -> atomic returns absolute slot) + s accumulation
__global__ __launch_bounds__(256) void k_fill_s(const int* __restrict__ row, const int* __restrict__ col,
                                                const float* __restrict__ inv_deg,
                                                int* __restrict__ cursor, int* __restrict__ csr,
                                                float* __restrict__ s) {
    int e = blockIdx.x * 256 + threadIdx.x;
    if (e < N_EDGES) {
        int c = col[e], r = row[e];
        int p = atomicAdd(&cursor[c], 1);
        csr[p] = r;
        atomicAdd(&s[c], inv_deg[r]);
    }
}

// ---------- fused GEMM. y=0: Pl(fp32)=x@W1.T ; y=1: Pi(bf16)=x@W2L.T ;
// y=2: Pj(bf16)=inv_deg[m]*(x@W2R.T) ----------
__global__ __launch_bounds__(256) void k_gemm(const ushort_t* __restrict__ xb,
                                              const float* __restrict__ W1,
                                              const float* __restrict__ W2,
                                              const float* __restrict__ inv_deg,
                                              float* __restrict__ Pl,
                                              ushort_t* __restrict__ Pi_,
                                              ushort_t* __restrict__ Pj) {
    __shared__ __align__(16) ushort_t As[64][136];   // +8 pad
    __shared__ __align__(16) ushort_t Bs[128][136];
    const int m0 = blockIdx.x * 64;
    const int y  = blockIdx.y;
    const float* Bp = (y == 0) ? W1 : (y == 1 ? W2 : W2 + 128);
    const int strideW = (y == 0) ? 128 : 256;
    const int tid = threadIdx.x;

    // stage A: 64 rows x 128 bf16
    #pragma unroll
    for (int it = 0; it < 4; ++it) {
        int chunk = tid + it * 256;
        int r = chunk >> 4, kc = chunk & 15;
        uint4 v = make_uint4(0, 0, 0, 0);
        int gm = m0 + r;
        if (gm < N_NODES) v = *(const uint4*)(xb + (size_t)gm * D + kc * 8);
        *(uint4*)&As[r][kc * 8] = v;
    }
    // stage B: 128 rows x 128 fp32 -> bf16
    #pragma unroll
    for (int it = 0; it < 16; ++it) {
        int c = tid + it * 256;
        int r = c >> 5, kc = c & 31;
        float4 v = *(const float4*)(Bp + r * strideW + kc * 4);
        ushort_t tmp[4] = { f2bf(v.x), f2bf(v.y), f2bf(v.z), f2bf(v.w) };
        *(uint2*)&Bs[r][kc * 4] = *(const uint2*)tmp;
    }
    __syncthreads();

    const int w = tid >> 6, lane = tid & 63, quad = lane >> 4, r16 = lane & 15;
    f32x4 acc[8];
    #pragma unroll
    for (int nt = 0; nt < 8; ++nt) acc[nt] = (f32x4){0.f, 0.f, 0.f, 0.f};
    const int arow = w * 16 + r16;
    #pragma unroll
    for (int k0 = 0; k0 < 128; k0 += 32) {
        bf16x8 a = __builtin_bit_cast(bf16x8, *(const uint4*)&As[arow][k0 + quad * 8]);
        #pragma unroll
        for (int nt = 0; nt < 8; ++nt) {
            bf16x8 b = __builtin_bit_cast(bf16x8, *(const uint4*)&Bs[nt * 16 + r16][k0 + quad * 8]);
            acc[nt] = __builtin_amdgcn_mfma_f32_16x16x32_bf16(a, b, acc[nt], 0, 0, 0);
        }
    }
    // C[m = w*16 + quad*4 + r][n = nt*16 + r16]
    float sc[4];
    #pragma unroll
    for (int r = 0; r < 4; ++r) {
        int gm = m0 + w * 16 + quad * 4 + r;
        sc[r] = (y == 2 && gm < N_NODES) ? inv_deg[gm] : 1.0f;
    }
    if (y == 0) {
        // fp32 scattered stores (16-lane x 4B = 64B contiguous segments)
        #pragma unroll
        for (int nt = 0; nt < 8; ++nt)
            #pragma unroll
            for (int r = 0; r < 4; ++r) {
                int gm = m0 + w * 16 + quad * 4 + r;
                if (gm < N_NODES) Pl[(size_t)gm * D + nt * 16 + r16] = acc[nt][r];
            }
    } else {
        // bf16: LDS transpose (reuse As) then coalesced uint4 stores
        ushort_t* Outp = (y == 1) ? Pi_ : Pj;
        __syncthreads();
        #pragma unroll
        for (int nt = 0; nt < 8; ++nt)
            #pragma unroll
            for (int r = 0; r < 4; ++r)
                As[w * 16 + quad * 4 + r][nt * 16 + r16] = f2bf(acc[nt][r] * sc[r]);
        __syncthreads();
        #pragma unroll
        for (int it = 0; it < 4; ++it) {
            int c = tid + it * 256;           // 1024 uint4 chunks: 64 rows x 16
            int rr = c >> 4, cc = c & 15;
            int gm = m0 + rr;
            if (gm < N_NODES) *(uint4*)(Outp + (size_t)gm * D + cc * 8) = *(const uint4*)&As[rr][cc * 8];
        }
    }
}

// ---------- per-node aggregation + exact GELU. One wave per node, 2 dims/lane ----------
__global__ __launch_bounds__(256) void k_agg(const float* __restrict__ Pl,
                                             const ushort_t* __restrict__ Pi_,
                                             const ushort_t* __restrict__ Pj,
                                             const int* __restrict__ off,
                                             const int* __restrict__ deg,
                                             const int* __restrict__ csr,
                                             const float* __restrict__ s,
                                             const float* __restrict__ bias,
                                             float* __restrict__ out_f32,
                                             ushort_t* __restrict__ out_bf16,
                                             int write_bf16) {
    int wv = __builtin_amdgcn_readfirstlane(threadIdx.x >> 6);   // force wave-uniform node
    int node = blockIdx.x * 4 + wv;
    int lane = threadIdx.x & 63;
    if (node >= N_NODES) return;
    float2 lin   = *(const float2*)(Pl + (size_t)node * D + 2 * lane);
    unsigned upi = *(const unsigned*)(Pi_ + (size_t)node * D + 2 * lane);
    float si = s[node];
    float2 bv = *(const float2*)(bias + 2 * lane);
    float a0 = lin.x + bv.x - si * bf2f(upi & 0xffffu);
    float a1 = lin.y + bv.y - si * bf2f(upi >> 16);
    float c0 = 0.f, c1 = 0.f;
    int e0 = off[node], ne = deg[node];
    int j = 0;
    for (; j + 4 <= ne; j += 4) {    // 4 gathers in flight, dual accumulators
        int s0 = csr[e0 + j], s1 = csr[e0 + j + 1], s2 = csr[e0 + j + 2], s3 = csr[e0 + j + 3];
        unsigned p0 = *(const unsigned*)(Pj + (size_t)s0 * D + 2 * lane);
        unsigned p1 = *(const unsigned*)(Pj + (size_t)s1 * D + 2 * lane);
        unsigned p2 = *(const unsigned*)(Pj + (size_t)s2 * D + 2 * lane);
        unsigned p3 = *(const unsigned*)(Pj + (size_t)s3 * D + 2 * lane);
        a0 -= bf2f(p0 & 0xffffu) + bf2f(p2 & 0xffffu);
        a1 -= bf2f(p0 >> 16)     + bf2f(p2 >> 16);
        c0 += bf2f(p1 & 0xffffu) + bf2f(p3 & 0xffffu);
        c1 += bf2f(p1 >> 16)     + bf2f(p3 >> 16);
    }
    for (; j < ne; ++j) {
        int s0 = csr[e0 + j];
        unsigned p0 = *(const unsigned*)(Pj + (size_t)s0 * D + 2 * lane);
        a0 -= bf2f(p0 & 0xffffu);
        a1 -= bf2f(p0 >> 16);
    }
    a0 -= c0; a1 -= c1;
    float g0 = 0.5f * a0 * (1.0f + erff(a0 * 0.70710678118654752440f));
    float g1 = 0.5f * a1 * (1.0f + erff(a1 * 0.70710678118654752440f));
    if (write_bf16) {
        ushort_t tmp[2] = { f2bf(g0), f2bf(g1) };
        *(unsigned*)(out_bf16 + (size_t)node * D + 2 * lane) = *(const unsigned*)tmp;
    } else {
        *(float2*)(out_f32 + (size_t)node * D + 2 * lane) = make_float2(g0, g1);
    }
}

extern "C" void kernel_launch(void* const* d_in, const int* in_sizes, int n_in,
                              void* d_out, int out_size, void* d_ws, size_t ws_size,
                              hipStream_t stream) {
    const float* x      = (const float*)d_in[0];
    const int*   ei     = (const int*)d_in[1];
    const int*   rowp   = ei;
    const int*   colp   = ei + N_EDGES;
    const float* W1s    = (const float*)d_in[2];
    const float* W2s    = (const float*)d_in[3];
    const float* biases = (const float*)d_in[4];
    float* out = (float*)d_out;

    char* ws = (char*)d_ws;
    size_t o = 0;
    auto carve = [&](size_t bytes) -> void* {
        void* p = ws + o;
        o = (o + bytes + 255) & ~(size_t)255;
        return p;
    };
    int*      deg     = (int*)carve(N_NODES * 4);
    int*      cursor  = (int*)carve(N_NODES * 4);
    float*    inv_deg = (float*)carve(N_NODES * 4);
    float*    s       = (float*)carve(N_NODES * 4);
    int*      off     = (int*)carve(N_NODES * 4);
    int*      bsum    = (int*)carve(NB2 * 4);
    int*      boff    = (int*)carve(NB2 * 4);
    int*      csr     = (int*)carve(N_EDGES * 4);
    ushort_t* xb      = (ushort_t*)carve((size_t)N_NODES * D * 2);
    float*    Pl      = (float*)carve((size_t)N_NODES * D * 4);
    ushort_t* Pi_     = (ushort_t*)carve((size_t)N_NODES * D * 2);
    ushort_t* Pj      = (ushort_t*)carve((size_t)N_NODES * D * 2);
    if (o > ws_size) return;   // diagnostic: absmax would read exactly 10.875

    hipMemsetAsync(deg, 0, N_NODES * 4, stream);
    hipMemsetAsync(s, 0, N_NODES * 4, stream);

    const int EB = (N_EDGES + 255) / 256;
    k_cast<<<(N_NODES * D / 4 + 255) / 256, 256, 0, stream>>>(x, xb);
    k_deg<<<EB, 256, 0, stream>>>(colp, deg);
    k_scan1<<<NB2, 256, 0, stream>>>(deg, bsum);
    k_scan2<<<1, 256, 0, stream>>>(bsum, boff);
    k_scan3<<<NB2, 256, 0, stream>>>(deg, boff, off, cursor, inv_deg);
    k_fill_s<<<EB, 256, 0, stream>>>(rowp, colp, inv_deg, cursor, csr, s);

    dim3 ggrid((N_NODES + 63) / 64, 3);
    const int AB = (N_NODES + 3) / 4;
    for (int k = 0; k < 2; ++k) {
        k_gemm<<<ggrid, 256, 0, stream>>>(xb, W1s + k * 128 * 128, W2s + k * 128 * 256,
                                          inv_deg, Pl, Pi_, Pj);
        k_agg<<<AB, 256, 0, stream>>>(Pl, Pi_, Pj, off, deg, csr, s, biases + k * 128,
                                      (k == 1) ? out : nullptr, xb, (k == 0) ? 1 : 0);
    }
}

// Round 3
// 289.723 us; speedup vs baseline: 1.8551x; 1.1120x over previous
//
#include <hip/hip_runtime.h>

#define N_NODES 50000
#define N_EDGES 800000
#define D 128
#define NB2 196   // ceil(N_NODES/256)
#define EPT 8     // edges per thread in atomic kernels (N_EDGES % 8 == 0)

typedef unsigned short ushort_t;
typedef __bf16 bf16x8 __attribute__((ext_vector_type(8)));
typedef float f32x4 __attribute__((ext_vector_type(4)));

__device__ __forceinline__ ushort_t f2bf(float f) {
    unsigned u = __builtin_bit_cast(unsigned, f);
    u += 0x7FFFu + ((u >> 16) & 1u);   // round-to-nearest-even
    return (ushort_t)(u >> 16);
}
__device__ __forceinline__ float bf2f(unsigned h16) {
    return __builtin_bit_cast(float, h16 << 16);
}

// ---------- graph setup ----------
// 8 edges/thread: 8 independent atomic chains in flight per lane (latency-bound fix)
__global__ __launch_bounds__(256) void k_deg(const int* __restrict__ col, int* __restrict__ deg) {
    int base = (blockIdx.x * 256 + threadIdx.x) * EPT;
    if (base >= N_EDGES) return;
    int4 c0 = *(const int4*)(col + base);
    int4 c1 = *(const int4*)(col + base + 4);
    atomicAdd(&deg[c0.x], 1); atomicAdd(&deg[c0.y], 1);
    atomicAdd(&deg[c0.z], 1); atomicAdd(&deg[c0.w], 1);
    atomicAdd(&deg[c1.x], 1); atomicAdd(&deg[c1.y], 1);
    atomicAdd(&deg[c1.z], 1); atomicAdd(&deg[c1.w], 1);
}

__global__ __launch_bounds__(256) void k_cast(const float* __restrict__ x, ushort_t* __restrict__ xb) {
    int i = blockIdx.x * 256 + threadIdx.x;    // one float4 per thread
    int base = i * 4;
    if (base < N_NODES * D) {
        float4 v = *(const float4*)(x + base);
        ushort_t tmp[4] = { f2bf(v.x), f2bf(v.y), f2bf(v.z), f2bf(v.w) };
        *(uint2*)(xb + base) = *(const uint2*)tmp;
    }
}

// 3-phase coalesced exclusive scan of deg -> off; also seeds cursor and inv_deg
__global__ __launch_bounds__(256) void k_scan1(const int* __restrict__ deg, int* __restrict__ bsum) {
    int i = blockIdx.x * 256 + threadIdx.x;
    int v = (i < N_NODES) ? deg[i] : 0;
    #pragma unroll
    for (int o = 32; o > 0; o >>= 1) v += __shfl_down(v, o, 64);
    __shared__ int wsum[4];
    if ((threadIdx.x & 63) == 0) wsum[threadIdx.x >> 6] = v;
    __syncthreads();
    if (threadIdx.x == 0) bsum[blockIdx.x] = wsum[0] + wsum[1] + wsum[2] + wsum[3];
}

__global__ __launch_bounds__(256) void k_scan2(const int* __restrict__ bsum, int* __restrict__ boff) {
    __shared__ int sm[256];
    int t = threadIdx.x;
    int v = (t < NB2) ? bsum[t] : 0;
    sm[t] = v;
    __syncthreads();
    for (int o = 1; o < 256; o <<= 1) {
        int add = (t >= o) ? sm[t - o] : 0;
        __syncthreads();
        sm[t] += add;
        __syncthreads();
    }
    if (t < NB2) boff[t] = sm[t] - v;   // exclusive
}

__global__ __launch_bounds__(256) void k_scan3(const int* __restrict__ deg, const int* __restrict__ boff,
                                               int* __restrict__ off, int* __restrict__ cursor,
                                               float* __restrict__ inv_deg) {
    __shared__ int sm[256];
    int t = threadIdx.x;
    int i = blockIdx.x * 256 + t;
    int d = (i < N_NODES) ? deg[i] : 0;
    sm[t] = d;
    __syncthreads();
    for (int o = 1; o < 256; o <<= 1) {
        int add = (t >= o) ? sm[t - o] : 0;
        __syncthreads();
        sm[t] += add;
        __syncthreads();
    }
    if (i < N_NODES) {
        int excl = sm[t] - d + boff[blockIdx.x];
        off[i] = excl;
        cursor[i] = excl;
        inv_deg[i] = 1.0f / (float)d;   // deg >= 1 guaranteed by construction
    }
}

// CSR fill, 8 edges/thread (cursor pre-seeded with off -> atomic returns absolute slot)
__global__ __launch_bounds__(256) void k_fill(const int* __restrict__ row, const int* __restrict__ col,
                                              int* __restrict__ cursor, int* __restrict__ csr) {
    int base = (blockIdx.x * 256 + threadIdx.x) * EPT;
    if (base >= N_EDGES) return;
    int4 c0 = *(const int4*)(col + base);
    int4 c1 = *(const int4*)(col + base + 4);
    int4 r0 = *(const int4*)(row + base);
    int4 r1 = *(const int4*)(row + base + 4);
    int p0 = atomicAdd(&cursor[c0.x], 1);
    int p1 = atomicAdd(&cursor[c0.y], 1);
    int p2 = atomicAdd(&cursor[c0.z], 1);
    int p3 = atomicAdd(&cursor[c0.w], 1);
    int p4 = atomicAdd(&cursor[c1.x], 1);
    int p5 = atomicAdd(&cursor[c1.y], 1);
    int p6 = atomicAdd(&cursor[c1.z], 1);
    int p7 = atomicAdd(&cursor[c1.w], 1);
    csr[p0] = r0.x; csr[p1] = r0.y; csr[p2] = r0.z; csr[p3] = r0.w;
    csr[p4] = r1.x; csr[p5] = r1.y; csr[p6] = r1.z; csr[p7] = r1.w;
}

// s[i] = sum of inv_deg[src] over i's CSR segment (no atomics, no memset)
__global__ __launch_bounds__(256) void k_s2(const int* __restrict__ off, const int* __restrict__ deg,
                                            const int* __restrict__ csr, const float* __restrict__ inv_deg,
                                            float* __restrict__ s) {
    int i = blockIdx.x * 256 + threadIdx.x;
    if (i >= N_NODES) return;
    int e0 = off[i], ne = deg[i];
    float a0 = 0.f, a1 = 0.f, a2 = 0.f, a3 = 0.f;
    int j = 0;
    for (; j + 4 <= ne; j += 4) {
        int i0 = csr[e0 + j], i1 = csr[e0 + j + 1], i2 = csr[e0 + j + 2], i3 = csr[e0 + j + 3];
        a0 += inv_deg[i0]; a1 += inv_deg[i1]; a2 += inv_deg[i2]; a3 += inv_deg[i3];
    }
    for (; j < ne; ++j) a0 += inv_deg[csr[e0 + j]];
    s[i] = (a0 + a1) + (a2 + a3);
}

// ---------- fused GEMM. y=0: Pl(fp32)=x@W1.T ; y=1: Pi(bf16)=x@W2L.T ;
// y=2: Pj(bf16)=inv_deg[m]*(x@W2R.T) ----------
__global__ __launch_bounds__(256) void k_gemm(const ushort_t* __restrict__ xb,
                                              const float* __restrict__ W1,
                                              const float* __restrict__ W2,
                                              const float* __restrict__ inv_deg,
                                              float* __restrict__ Pl,
                                              ushort_t* __restrict__ Pi_,
                                              ushort_t* __restrict__ Pj) {
    __shared__ __align__(16) ushort_t As[64][136];   // +8 pad
    __shared__ __align__(16) ushort_t Bs[128][136];
    const int m0 = blockIdx.x * 64;
    const int y  = blockIdx.y;
    const float* Bp = (y == 0) ? W1 : (y == 1 ? W2 : W2 + 128);
    const int strideW = (y == 0) ? 128 : 256;
    const int tid = threadIdx.x;

    #pragma unroll
    for (int it = 0; it < 4; ++it) {
        int chunk = tid + it * 256;
        int r = chunk >> 4, kc = chunk & 15;
        uint4 v = make_uint4(0, 0, 0, 0);
        int gm = m0 + r;
        if (gm < N_NODES) v = *(const uint4*)(xb + (size_t)gm * D + kc * 8);
        *(uint4*)&As[r][kc * 8] = v;
    }
    #pragma unroll
    for (int it = 0; it < 16; ++it) {
        int c = tid + it * 256;
        int r = c >> 5, kc = c & 31;
        float4 v = *(const float4*)(Bp + r * strideW + kc * 4);
        ushort_t tmp[4] = { f2bf(v.x), f2bf(v.y), f2bf(v.z), f2bf(v.w) };
        *(uint2*)&Bs[r][kc * 4] = *(const uint2*)tmp;
    }
    __syncthreads();

    const int w = tid >> 6, lane = tid & 63, quad = lane >> 4, r16 = lane & 15;
    f32x4 acc[8];
    #pragma unroll
    for (int nt = 0; nt < 8; ++nt) acc[nt] = (f32x4){0.f, 0.f, 0.f, 0.f};
    const int arow = w * 16 + r16;
    #pragma unroll
    for (int k0 = 0; k0 < 128; k0 += 32) {
        bf16x8 a = __builtin_bit_cast(bf16x8, *(const uint4*)&As[arow][k0 + quad * 8]);
        #pragma unroll
        for (int nt = 0; nt < 8; ++nt) {
            bf16x8 b = __builtin_bit_cast(bf16x8, *(const uint4*)&Bs[nt * 16 + r16][k0 + quad * 8]);
            acc[nt] = __builtin_amdgcn_mfma_f32_16x16x32_bf16(a, b, acc[nt], 0, 0, 0);
        }
    }
    // C[m = w*16 + quad*4 + r][n = nt*16 + r16]
    float sc[4];
    #pragma unroll
    for (int r = 0; r < 4; ++r) {
        int gm = m0 + w * 16 + quad * 4 + r;
        sc[r] = (y == 2 && gm < N_NODES) ? inv_deg[gm] : 1.0f;
    }
    if (y == 0) {
        #pragma unroll
        for (int nt = 0; nt < 8; ++nt)
            #pragma unroll
            for (int r = 0; r < 4; ++r) {
                int gm = m0 + w * 16 + quad * 4 + r;
                if (gm < N_NODES) Pl[(size_t)gm * D + nt * 16 + r16] = acc[nt][r];
            }
    } else {
        ushort_t* Outp = (y == 1) ? Pi_ : Pj;
        __syncthreads();
        #pragma unroll
        for (int nt = 0; nt < 8; ++nt)
            #pragma unroll
            for (int r = 0; r < 4; ++r)
                As[w * 16 + quad * 4 + r][nt * 16 + r16] = f2bf(acc[nt][r] * sc[r]);
        __syncthreads();
        #pragma unroll
        for (int it = 0; it < 4; ++it) {
            int c = tid + it * 256;           // 1024 uint4 chunks: 64 rows x 16
            int rr = c >> 4, cc = c & 15;
            int gm = m0 + rr;
            if (gm < N_NODES) *(uint4*)(Outp + (size_t)gm * D + cc * 8) = *(const uint4*)&As[rr][cc * 8];
        }
    }
}

// ---------- per-node aggregation + exact GELU. One wave per node, 2 dims/lane ----------
__global__ __launch_bounds__(256) void k_agg(const float* __restrict__ Pl,
                                             const ushort_t* __restrict__ Pi_,
                                             const ushort_t* __restrict__ Pj,
                                             const int* __restrict__ off,
                                             const int* __restrict__ deg,
                                             const int* __restrict__ csr,
                                             const float* __restrict__ s,
                                             const float* __restrict__ bias,
                                             float* __restrict__ out_f32,
                                             ushort_t* __restrict__ out_bf16,
                                             int write_bf16) {
    int wv = __builtin_amdgcn_readfirstlane(threadIdx.x >> 6);   // wave-uniform node
    int node = blockIdx.x * 4 + wv;
    int lane = threadIdx.x & 63;
    if (node >= N_NODES) return;
    float2 lin   = *(const float2*)(Pl + (size_t)node * D + 2 * lane);
    unsigned upi = *(const unsigned*)(Pi_ + (size_t)node * D + 2 * lane);
    float si = s[node];
    float2 bv = *(const float2*)(bias + 2 * lane);
    float a0 = lin.x + bv.x - si * bf2f(upi & 0xffffu);
    float a1 = lin.y + bv.y - si * bf2f(upi >> 16);
    float c0 = 0.f, c1 = 0.f;
    int e0 = off[node], ne = deg[node];
    int j = 0;
    for (; j + 8 <= ne; j += 8) {    // 8 gathers in flight, dual accumulators
        int s0 = csr[e0 + j],     s1 = csr[e0 + j + 1], s2 = csr[e0 + j + 2], s3 = csr[e0 + j + 3];
        int s4 = csr[e0 + j + 4], s5 = csr[e0 + j + 5], s6 = csr[e0 + j + 6], s7 = csr[e0 + j + 7];
        unsigned p0 = *(const unsigned*)(Pj + (size_t)s0 * D + 2 * lane);
        unsigned p1 = *(const unsigned*)(Pj + (size_t)s1 * D + 2 * lane);
        unsigned p2 = *(const unsigned*)(Pj + (size_t)s2 * D + 2 * lane);
        unsigned p3 = *(const unsigned*)(Pj + (size_t)s3 * D + 2 * lane);
        unsigned p4 = *(const unsigned*)(Pj + (size_t)s4 * D + 2 * lane);
        unsigned p5 = *(const unsigned*)(Pj + (size_t)s5 * D + 2 * lane);
        unsigned p6 = *(const unsigned*)(Pj + (size_t)s6 * D + 2 * lane);
        unsigned p7 = *(const unsigned*)(Pj + (size_t)s7 * D + 2 * lane);
        a0 -= (bf2f(p0 & 0xffffu) + bf2f(p2 & 0xffffu)) + (bf2f(p4 & 0xffffu) + bf2f(p6 & 0xffffu));
        a1 -= (bf2f(p0 >> 16)     + bf2f(p2 >> 16))     + (bf2f(p4 >> 16)     + bf2f(p6 >> 16));
        c0 += (bf2f(p1 & 0xffffu) + bf2f(p3 & 0xffffu)) + (bf2f(p5 & 0xffffu) + bf2f(p7 & 0xffffu));
        c1 += (bf2f(p1 >> 16)     + bf2f(p3 >> 16))     + (bf2f(p5 >> 16)     + bf2f(p7 >> 16));
    }
    for (; j + 4 <= ne; j += 4) {
        int s0 = csr[e0 + j], s1 = csr[e0 + j + 1], s2 = csr[e0 + j + 2], s3 = csr[e0 + j + 3];
        unsigned p0 = *(const unsigned*)(Pj + (size_t)s0 * D + 2 * lane);
        unsigned p1 = *(const unsigned*)(Pj + (size_t)s1 * D + 2 * lane);
        unsigned p2 = *(const unsigned*)(Pj + (size_t)s2 * D + 2 * lane);
        unsigned p3 = *(const unsigned*)(Pj + (size_t)s3 * D + 2 * lane);
        a0 -= bf2f(p0 & 0xffffu) + bf2f(p2 & 0xffffu);
        a1 -= bf2f(p0 >> 16)     + bf2f(p2 >> 16);
        c0 += bf2f(p1 & 0xffffu) + bf2f(p3 & 0xffffu);
        c1 += bf2f(p1 >> 16)     + bf2f(p3 >> 16);
    }
    for (; j < ne; ++j) {
        int s0 = csr[e0 + j];
        unsigned p0 = *(const unsigned*)(Pj + (size_t)s0 * D + 2 * lane);
        a0 -= bf2f(p0 & 0xffffu);
        a1 -= bf2f(p0 >> 16);
    }
    a0 -= c0; a1 -= c1;
    float g0 = 0.5f * a0 * (1.0f + erff(a0 * 0.70710678118654752440f));
    float g1 = 0.5f * a1 * (1.0f + erff(a1 * 0.70710678118654752440f));
    if (write_bf16) {
        ushort_t tmp[2] = { f2bf(g0), f2bf(g1) };
        *(unsigned*)(out_bf16 + (size_t)node * D + 2 * lane) = *(const unsigned*)tmp;
    } else {
        *(float2*)(out_f32 + (size_t)node * D + 2 * lane) = make_float2(g0, g1);
    }
}

extern "C" void kernel_launch(void* const* d_in, const int* in_sizes, int n_in,
                              void* d_out, int out_size, void* d_ws, size_t ws_size,
                              hipStream_t stream) {
    const float* x      = (const float*)d_in[0];
    const int*   ei     = (const int*)d_in[1];
    const int*   rowp   = ei;
    const int*   colp   = ei + N_EDGES;
    const float* W1s    = (const float*)d_in[2];
    const float* W2s    = (const float*)d_in[3];
    const float* biases = (const float*)d_in[4];
    float* out = (float*)d_out;

    char* ws = (char*)d_ws;
    size_t o = 0;
    auto carve = [&](size_t bytes) -> void* {
        void* p = ws + o;
        o = (o + bytes + 255) & ~(size_t)255;
        return p;
    };
    int*      deg     = (int*)carve(N_NODES * 4);
    int*      cursor  = (int*)carve(N_NODES * 4);
    float*    inv_deg = (float*)carve(N_NODES * 4);
    float*    s       = (float*)carve(N_NODES * 4);
    int*      off     = (int*)carve(N_NODES * 4);
    int*      bsum    = (int*)carve(NB2 * 4);
    int*      boff    = (int*)carve(NB2 * 4);
    int*      csr     = (int*)carve(N_EDGES * 4);
    ushort_t* xb      = (ushort_t*)carve((size_t)N_NODES * D * 2);
    float*    Pl      = (float*)carve((size_t)N_NODES * D * 4);
    ushort_t* Pi_     = (ushort_t*)carve((size_t)N_NODES * D * 2);
    ushort_t* Pj      = (ushort_t*)carve((size_t)N_NODES * D * 2);
    if (o > ws_size) return;   // diagnostic: absmax would read exactly 10.875

    hipMemsetAsync(deg, 0, N_NODES * 4, stream);

    const int EB8 = (N_EDGES / EPT + 255) / 256;
    k_cast<<<(N_NODES * D / 4 + 255) / 256, 256, 0, stream>>>(x, xb);
    k_deg<<<EB8, 256, 0, stream>>>(colp, deg);
    k_scan1<<<NB2, 256, 0, stream>>>(deg, bsum);
    k_scan2<<<1, 256, 0, stream>>>(bsum, boff);
    k_scan3<<<NB2, 256, 0, stream>>>(deg, boff, off, cursor, inv_deg);
    k_fill<<<EB8, 256, 0, stream>>>(rowp, colp, cursor, csr);
    k_s2<<<NB2, 256, 0, stream>>>(off, deg, csr, inv_deg, s);

    dim3 ggrid((N_NODES + 63) / 64, 3);
    const int AB = (N_NODES + 3) / 4;
    for (int k = 0; k < 2; ++k) {
        k_gemm<<<ggrid, 256, 0, stream>>>(xb, W1s + k * 128 * 128, W2s + k * 128 * 256,
                                          inv_deg, Pl, Pi_, Pj);
        k_agg<<<AB, 256, 0, stream>>>(Pl, Pi_, Pj, off, deg, csr, s, biases + k * 128,
                                      (k == 1) ? out : nullptr, xb, (k == 0) ? 1 : 0);
    }
}

// Round 4
// 265.715 us; speedup vs baseline: 2.0227x; 1.0904x over previous
//
#include <hip/hip_runtime.h>

#define N_NODES 50000
#define N_EDGES 800000
#define D 128
#define NB2 196          // ceil(N_NODES/256)
#define EPT 8            // edges per thread in atomic kernels (N_EDGES % 8 == 0)
#define DEG_BLOCKS 391   // ceil(N_EDGES/EPT/256)
#define CAST_BLOCKS 6250 // N_NODES*D/4/256
#define GEMM_TILES 782   // ceil(N_NODES/64)

typedef unsigned short ushort_t;
typedef __bf16 bf16x8 __attribute__((ext_vector_type(8)));
typedef float f32x4 __attribute__((ext_vector_type(4)));

__device__ __forceinline__ ushort_t f2bf(float f) {
    unsigned u = __builtin_bit_cast(unsigned, f);
    u += 0x7FFFu + ((u >> 16) & 1u);   // round-to-nearest-even
    return (ushort_t)(u >> 16);
}
__device__ __forceinline__ float bf2f(unsigned h16) {
    return __builtin_bit_cast(float, h16 << 16);
}

// ---------- fused: deg atomics (first 391 blocks) + x fp32->bf16 cast (rest) ----------
__global__ __launch_bounds__(256) void k_cast_deg(const float* __restrict__ x, ushort_t* __restrict__ xb,
                                                  const int* __restrict__ col, int* __restrict__ deg) {
    int b = blockIdx.x;
    if (b < DEG_BLOCKS) {
        int base = (b * 256 + threadIdx.x) * EPT;
        if (base >= N_EDGES) return;
        int4 c0 = *(const int4*)(col + base);
        int4 c1 = *(const int4*)(col + base + 4);
        atomicAdd(&deg[c0.x], 1); atomicAdd(&deg[c0.y], 1);
        atomicAdd(&deg[c0.z], 1); atomicAdd(&deg[c0.w], 1);
        atomicAdd(&deg[c1.x], 1); atomicAdd(&deg[c1.y], 1);
        atomicAdd(&deg[c1.z], 1); atomicAdd(&deg[c1.w], 1);
    } else {
        int base = ((b - DEG_BLOCKS) * 256 + threadIdx.x) * 4;
        if (base < N_NODES * D) {
            float4 v = *(const float4*)(x + base);
            ushort_t tmp[4] = { f2bf(v.x), f2bf(v.y), f2bf(v.z), f2bf(v.w) };
            *(uint2*)(xb + base) = *(const uint2*)tmp;
        }
    }
}

// ---------- 3-phase coalesced exclusive scan of deg -> off; seeds cursor & inv_deg ----------
__global__ __launch_bounds__(256) void k_scan1(const int* __restrict__ deg, int* __restrict__ bsum) {
    int i = blockIdx.x * 256 + threadIdx.x;
    int v = (i < N_NODES) ? deg[i] : 0;
    #pragma unroll
    for (int o = 32; o > 0; o >>= 1) v += __shfl_down(v, o, 64);
    __shared__ int wsum[4];
    if ((threadIdx.x & 63) == 0) wsum[threadIdx.x >> 6] = v;
    __syncthreads();
    if (threadIdx.x == 0) bsum[blockIdx.x] = wsum[0] + wsum[1] + wsum[2] + wsum[3];
}

__global__ __launch_bounds__(256) void k_scan2(const int* __restrict__ bsum, int* __restrict__ boff) {
    __shared__ int sm[256];
    int t = threadIdx.x;
    int v = (t < NB2) ? bsum[t] : 0;
    sm[t] = v;
    __syncthreads();
    for (int o = 1; o < 256; o <<= 1) {
        int add = (t >= o) ? sm[t - o] : 0;
        __syncthreads();
        sm[t] += add;
        __syncthreads();
    }
    if (t < NB2) boff[t] = sm[t] - v;   // exclusive
}

__global__ __launch_bounds__(256) void k_scan3(const int* __restrict__ deg, const int* __restrict__ boff,
                                               int* __restrict__ off, int* __restrict__ cursor,
                                               float* __restrict__ inv_deg) {
    __shared__ int sm[256];
    int t = threadIdx.x;
    int i = blockIdx.x * 256 + t;
    int d = (i < N_NODES) ? deg[i] : 0;
    sm[t] = d;
    __syncthreads();
    for (int o = 1; o < 256; o <<= 1) {
        int add = (t >= o) ? sm[t - o] : 0;
        __syncthreads();
        sm[t] += add;
        __syncthreads();
    }
    if (i < N_NODES) {
        int excl = sm[t] - d + boff[blockIdx.x];
        off[i] = excl;
        cursor[i] = excl;
        inv_deg[i] = 1.0f / (float)d;   // deg >= 1 by construction
    }
}

// ---------- shared GEMM tile body. y=0: Plb=x@W1.T ; y=1: Pi=x@W2L.T ; y=2: Pj=inv_deg*(x@W2R.T)
// All outputs bf16, LDS-transposed, uint4-coalesced. ----------
__device__ __forceinline__ void gemm_tile(int m0, int y,
                                          ushort_t (*As)[136], ushort_t (*Bs)[136],
                                          const ushort_t* __restrict__ xb,
                                          const float* __restrict__ W1,
                                          const float* __restrict__ W2,
                                          const float* __restrict__ inv_deg,
                                          ushort_t* __restrict__ Plb,
                                          ushort_t* __restrict__ Pi_,
                                          ushort_t* __restrict__ Pj) {
    const float* Bp = (y == 0) ? W1 : (y == 1 ? W2 : W2 + 128);
    const int strideW = (y == 0) ? 128 : 256;
    const int tid = threadIdx.x;

    #pragma unroll
    for (int it = 0; it < 4; ++it) {
        int chunk = tid + it * 256;
        int r = chunk >> 4, kc = chunk & 15;
        uint4 v = make_uint4(0, 0, 0, 0);
        int gm = m0 + r;
        if (gm < N_NODES) v = *(const uint4*)(xb + (size_t)gm * D + kc * 8);
        *(uint4*)&As[r][kc * 8] = v;
    }
    #pragma unroll
    for (int it = 0; it < 16; ++it) {
        int c = tid + it * 256;
        int r = c >> 5, kc = c & 31;
        float4 v = *(const float4*)(Bp + r * strideW + kc * 4);
        ushort_t tmp[4] = { f2bf(v.x), f2bf(v.y), f2bf(v.z), f2bf(v.w) };
        *(uint2*)&Bs[r][kc * 4] = *(const uint2*)tmp;
    }
    __syncthreads();

    const int w = tid >> 6, lane = tid & 63, quad = lane >> 4, r16 = lane & 15;
    f32x4 acc[8];
    #pragma unroll
    for (int nt = 0; nt < 8; ++nt) acc[nt] = (f32x4){0.f, 0.f, 0.f, 0.f};
    const int arow = w * 16 + r16;
    #pragma unroll
    for (int k0 = 0; k0 < 128; k0 += 32) {
        bf16x8 a = __builtin_bit_cast(bf16x8, *(const uint4*)&As[arow][k0 + quad * 8]);
        #pragma unroll
        for (int nt = 0; nt < 8; ++nt) {
            bf16x8 b = __builtin_bit_cast(bf16x8, *(const uint4*)&Bs[nt * 16 + r16][k0 + quad * 8]);
            acc[nt] = __builtin_amdgcn_mfma_f32_16x16x32_bf16(a, b, acc[nt], 0, 0, 0);
        }
    }
    // C[m = w*16 + quad*4 + r][n = nt*16 + r16]; epilogue via LDS transpose (reuse As)
    float sc[4];
    #pragma unroll
    for (int r = 0; r < 4; ++r) {
        int gm = m0 + w * 16 + quad * 4 + r;
        sc[r] = (y == 2 && gm < N_NODES) ? inv_deg[gm] : 1.0f;
    }
    ushort_t* Outp = (y == 0) ? Plb : (y == 1 ? Pi_ : Pj);
    __syncthreads();
    #pragma unroll
    for (int nt = 0; nt < 8; ++nt)
        #pragma unroll
        for (int r = 0; r < 4; ++r)
            As[w * 16 + quad * 4 + r][nt * 16 + r16] = f2bf(acc[nt][r] * sc[r]);
    __syncthreads();
    #pragma unroll
    for (int it = 0; it < 4; ++it) {
        int c = tid + it * 256;           // 1024 uint4 chunks: 64 rows x 16
        int rr = c >> 4, cc = c & 15;
        int gm = m0 + rr;
        if (gm < N_NODES) *(uint4*)(Outp + (size_t)gm * D + cc * 8) = *(const uint4*)&As[rr][cc * 8];
    }
}

// ---------- fused: CSR fill (first 391 blocks, latency-bound) + layer-0 GEMM (rest) ----------
__global__ __launch_bounds__(256) void k_fill_gemm(const int* __restrict__ row, const int* __restrict__ col,
                                                   int* __restrict__ cursor, int* __restrict__ csr,
                                                   const ushort_t* __restrict__ xb,
                                                   const float* __restrict__ W1,
                                                   const float* __restrict__ W2,
                                                   const float* __restrict__ inv_deg,
                                                   ushort_t* __restrict__ Plb,
                                                   ushort_t* __restrict__ Pi_,
                                                   ushort_t* __restrict__ Pj) {
    __shared__ __align__(16) ushort_t As[64][136];
    __shared__ __align__(16) ushort_t Bs[128][136];
    if (blockIdx.x < DEG_BLOCKS) {
        int base = (blockIdx.x * 256 + threadIdx.x) * EPT;
        if (base >= N_EDGES) return;
        int4 c0 = *(const int4*)(col + base);
        int4 c1 = *(const int4*)(col + base + 4);
        int4 r0 = *(const int4*)(row + base);
        int4 r1 = *(const int4*)(row + base + 4);
        int p0 = atomicAdd(&cursor[c0.x], 1);
        int p1 = atomicAdd(&cursor[c0.y], 1);
        int p2 = atomicAdd(&cursor[c0.z], 1);
        int p3 = atomicAdd(&cursor[c0.w], 1);
        int p4 = atomicAdd(&cursor[c1.x], 1);
        int p5 = atomicAdd(&cursor[c1.y], 1);
        int p6 = atomicAdd(&cursor[c1.z], 1);
        int p7 = atomicAdd(&cursor[c1.w], 1);
        csr[p0] = r0.x; csr[p1] = r0.y; csr[p2] = r0.z; csr[p3] = r0.w;
        csr[p4] = r1.x; csr[p5] = r1.y; csr[p6] = r1.z; csr[p7] = r1.w;
    } else {
        int g = blockIdx.x - DEG_BLOCKS;
        int y = g % 3, tile = g / 3;     // same tile adjacent -> xb L2 locality
        gemm_tile(tile * 64, y, As, Bs, xb, W1, W2, inv_deg, Plb, Pi_, Pj);
    }
}

// ---------- standalone GEMM (layer 1) ----------
__global__ __launch_bounds__(256) void k_gemm(const ushort_t* __restrict__ xb,
                                              const float* __restrict__ W1,
                                              const float* __restrict__ W2,
                                              const float* __restrict__ inv_deg,
                                              ushort_t* __restrict__ Plb,
                                              ushort_t* __restrict__ Pi_,
                                              ushort_t* __restrict__ Pj) {
    __shared__ __align__(16) ushort_t As[64][136];
    __shared__ __align__(16) ushort_t Bs[128][136];
    gemm_tile(blockIdx.x * 64, blockIdx.y, As, Bs, xb, W1, W2, inv_deg, Plb, Pi_, Pj);
}

// ---------- per-node aggregation + exact GELU; si computed inline. One wave/node ----------
__global__ __launch_bounds__(256) void k_agg(const ushort_t* __restrict__ Plb,
                                             const ushort_t* __restrict__ Pi_,
                                             const ushort_t* __restrict__ Pj,
                                             const int* __restrict__ off,
                                             const int* __restrict__ deg,
                                             const int* __restrict__ csr,
                                             const float* __restrict__ inv_deg,
                                             const float* __restrict__ bias,
                                             float* __restrict__ out_f32,
                                             ushort_t* __restrict__ out_bf16,
                                             int write_bf16) {
    int wv = __builtin_amdgcn_readfirstlane(threadIdx.x >> 6);   // wave-uniform node
    int node = blockIdx.x * 4 + wv;
    int lane = threadIdx.x & 63;
    if (node >= N_NODES) return;
    unsigned ulin = *(const unsigned*)(Plb + (size_t)node * D + 2 * lane);
    unsigned upi  = *(const unsigned*)(Pi_ + (size_t)node * D + 2 * lane);
    float2 bv = *(const float2*)(bias + 2 * lane);
    float a0 = bf2f(ulin & 0xffffu) + bv.x;
    float a1 = bf2f(ulin >> 16)     + bv.y;
    float c0 = 0.f, c1 = 0.f, si = 0.f;
    int e0 = off[node], ne = deg[node];
    int j = 0;
    for (; j + 8 <= ne; j += 8) {    // 8 gathers in flight, dual accumulators
        int s0 = csr[e0 + j],     s1 = csr[e0 + j + 1], s2 = csr[e0 + j + 2], s3 = csr[e0 + j + 3];
        int s4 = csr[e0 + j + 4], s5 = csr[e0 + j + 5], s6 = csr[e0 + j + 6], s7 = csr[e0 + j + 7];
        unsigned p0 = *(const unsigned*)(Pj + (size_t)s0 * D + 2 * lane);
        unsigned p1 = *(const unsigned*)(Pj + (size_t)s1 * D + 2 * lane);
        unsigned p2 = *(const unsigned*)(Pj + (size_t)s2 * D + 2 * lane);
        unsigned p3 = *(const unsigned*)(Pj + (size_t)s3 * D + 2 * lane);
        unsigned p4 = *(const unsigned*)(Pj + (size_t)s4 * D + 2 * lane);
        unsigned p5 = *(const unsigned*)(Pj + (size_t)s5 * D + 2 * lane);
        unsigned p6 = *(const unsigned*)(Pj + (size_t)s6 * D + 2 * lane);
        unsigned p7 = *(const unsigned*)(Pj + (size_t)s7 * D + 2 * lane);
        si += ((inv_deg[s0] + inv_deg[s1]) + (inv_deg[s2] + inv_deg[s3]))
            + ((inv_deg[s4] + inv_deg[s5]) + (inv_deg[s6] + inv_deg[s7]));
        a0 -= (bf2f(p0 & 0xffffu) + bf2f(p2 & 0xffffu)) + (bf2f(p4 & 0xffffu) + bf2f(p6 & 0xffffu));
        a1 -= (bf2f(p0 >> 16)     + bf2f(p2 >> 16))     + (bf2f(p4 >> 16)     + bf2f(p6 >> 16));
        c0 += (bf2f(p1 & 0xffffu) + bf2f(p3 & 0xffffu)) + (bf2f(p5 & 0xffffu) + bf2f(p7 & 0xffffu));
        c1 += (bf2f(p1 >> 16)     + bf2f(p3 >> 16))     + (bf2f(p5 >> 16)     + bf2f(p7 >> 16));
    }
    for (; j + 4 <= ne; j += 4) {
        int s0 = csr[e0 + j], s1 = csr[e0 + j + 1], s2 = csr[e0 + j + 2], s3 = csr[e0 + j + 3];
        unsigned p0 = *(const unsigned*)(Pj + (size_t)s0 * D + 2 * lane);
        unsigned p1 = *(const unsigned*)(Pj + (size_t)s1 * D + 2 * lane);
        unsigned p2 = *(const unsigned*)(Pj + (size_t)s2 * D + 2 * lane);
        unsigned p3 = *(const unsigned*)(Pj + (size_t)s3 * D + 2 * lane);
        si += (inv_deg[s0] + inv_deg[s1]) + (inv_deg[s2] + inv_deg[s3]);
        a0 -= bf2f(p0 & 0xffffu) + bf2f(p2 & 0xffffu);
        a1 -= bf2f(p0 >> 16)     + bf2f(p2 >> 16);
        c0 += bf2f(p1 & 0xffffu) + bf2f(p3 & 0xffffu);
        c1 += bf2f(p1 >> 16)     + bf2f(p3 >> 16);
    }
    for (; j < ne; ++j) {
        int s0 = csr[e0 + j];
        unsigned p0 = *(const unsigned*)(Pj + (size_t)s0 * D + 2 * lane);
        si += inv_deg[s0];
        a0 -= bf2f(p0 & 0xffffu);
        a1 -= bf2f(p0 >> 16);
    }
    a0 -= c0 + si * bf2f(upi & 0xffffu);
    a1 -= c1 + si * bf2f(upi >> 16);
    float g0 = 0.5f * a0 * (1.0f + erff(a0 * 0.70710678118654752440f));
    float g1 = 0.5f * a1 * (1.0f + erff(a1 * 0.70710678118654752440f));
    if (write_bf16) {
        ushort_t tmp[2] = { f2bf(g0), f2bf(g1) };
        *(unsigned*)(out_bf16 + (size_t)node * D + 2 * lane) = *(const unsigned*)tmp;
    } else {
        *(float2*)(out_f32 + (size_t)node * D + 2 * lane) = make_float2(g0, g1);
    }
}

extern "C" void kernel_launch(void* const* d_in, const int* in_sizes, int n_in,
                              void* d_out, int out_size, void* d_ws, size_t ws_size,
                              hipStream_t stream) {
    const float* x      = (const float*)d_in[0];
    const int*   ei     = (const int*)d_in[1];
    const int*   rowp   = ei;
    const int*   colp   = ei + N_EDGES;
    const float* W1s    = (const float*)d_in[2];
    const float* W2s    = (const float*)d_in[3];
    const float* biases = (const float*)d_in[4];
    float* out = (float*)d_out;

    char* ws = (char*)d_ws;
    size_t o = 0;
    auto carve = [&](size_t bytes) -> void* {
        void* p = ws + o;
        o = (o + bytes + 255) & ~(size_t)255;
        return p;
    };
    int*      deg     = (int*)carve(N_NODES * 4);
    int*      cursor  = (int*)carve(N_NODES * 4);
    float*    inv_deg = (float*)carve(N_NODES * 4);
    int*      off     = (int*)carve(N_NODES * 4);
    int*      bsum    = (int*)carve(NB2 * 4);
    int*      boff    = (int*)carve(NB2 * 4);
    int*      csr     = (int*)carve(N_EDGES * 4);
    ushort_t* xb      = (ushort_t*)carve((size_t)N_NODES * D * 2);
    ushort_t* Plb     = (ushort_t*)carve((size_t)N_NODES * D * 2);
    ushort_t* Pi_     = (ushort_t*)carve((size_t)N_NODES * D * 2);
    ushort_t* Pj      = (ushort_t*)carve((size_t)N_NODES * D * 2);
    if (o > ws_size) return;   // diagnostic: absmax would read exactly 10.875

    hipMemsetAsync(deg, 0, N_NODES * 4, stream);

    k_cast_deg<<<DEG_BLOCKS + CAST_BLOCKS, 256, 0, stream>>>(x, xb, colp, deg);
    k_scan1<<<NB2, 256, 0, stream>>>(deg, bsum);
    k_scan2<<<1, 256, 0, stream>>>(bsum, boff);
    k_scan3<<<NB2, 256, 0, stream>>>(deg, boff, off, cursor, inv_deg);

    const int AB = (N_NODES + 3) / 4;
    // layer 0: CSR fill overlapped with GEMM
    k_fill_gemm<<<DEG_BLOCKS + 3 * GEMM_TILES, 256, 0, stream>>>(rowp, colp, cursor, csr, xb,
                                                                 W1s, W2s, inv_deg, Plb, Pi_, Pj);
    k_agg<<<AB, 256, 0, stream>>>(Plb, Pi_, Pj, off, deg, csr, inv_deg, biases,
                                  nullptr, xb, 1);
    // layer 1
    k_gemm<<<dim3(GEMM_TILES, 3), 256, 0, stream>>>(xb, W1s + 128 * 128, W2s + 128 * 256,
                                                    inv_deg, Plb, Pi_, Pj);
    k_agg<<<AB, 256, 0, stream>>>(Plb, Pi_, Pj, off, deg, csr, inv_deg, biases + 128,
                                  out, nullptr, 0);
}